// Round 9
// baseline (12917.241 us; speedup 1.0000x reference)
//
#include <hip/hip_runtime.h>
#include <cstdint>
#include <cstddef>

// Problem constants
#define BB    64
#define TT    400
#define NN    1024
#define NIN   128
#define NOUT  32
#define DD    3
#define LL6   6        // ring length (delays 1,2,4)
#define GG    16       // batch groups
#define BPG   4        // batches per group
#define NT    32       // column tiles
#define KK    3072     // D*N

#define ALPHA_MEM     0.95f
#define ALPHA_MEM_OUT 0.95f
#define ALPHA_P       0.99f

// ---------------------------------------------------------------------------
// Blocked W: Wb[tile][kk][c] = dmap[d][e][tile*32+c] * sign[e]*|w[e][tile*32+c]|
// (tile 0..31, kk = d*1024+e in 0..3071, c 0..31). Per-tile 384 KB contiguous.
// ---------------------------------------------------------------------------
__global__ void build_W(const float* __restrict__ w,
                        const float* __restrict__ w_signs,
                        const float* __restrict__ dmap,
                        float* __restrict__ Wb) {
    int idx = blockIdx.x * blockDim.x + threadIdx.x;
    if (idx >= DD * NN * NN) return;
    const int tile = idx / (KK * 32);
    const int rem  = idx % (KK * 32);
    const int kk   = rem >> 5;
    const int c    = rem & 31;
    const int e    = kk & 1023;
    const int col  = tile * 32 + c;
    Wb[idx] = dmap[(size_t)kk * NN + col] * (w_signs[e] * fabsf(w[(size_t)e * NN + col]));
}

// inp_pre laid out [t][b][n]
__global__ void gemm_in(const float* __restrict__ inputs,
                        const float* __restrict__ w_in,
                        float* __restrict__ inp) {
    int idx = blockIdx.x * blockDim.x + threadIdx.x;
    if (idx >= TT * BB * NN) return;
    int n  = idx & (NN - 1);
    int tb = idx >> 10;
    int b  = tb & 63;
    int t  = tb >> 6;
    const float* row = inputs + ((size_t)b * TT + t) * NIN;
    float acc = 0.0f;
    #pragma unroll 8
    for (int c = 0; c < NIN; ++c)
        acc = fmaf(row[c], w_in[c * NN + n], acc);
    inp[idx] = acc;
}

// zero through the coherent point so agent-scope readers see it
__global__ void zero_sc1(float* __restrict__ p, int n) {
    int i = blockIdx.x * blockDim.x + threadIdx.x;
    if (i < n)
        __hip_atomic_store(p + i, 0.0f, __ATOMIC_RELAXED, __HIP_MEMORY_SCOPE_AGENT);
}

// ---------------------------------------------------------------------------
// 512 blocks x 256 threads, 2 blocks/CU. Block (g=bid>>5, tile=bid&31) owns
// 4 batches x 32 cols and computes their full-k GEMM. Ring exchange via
// IF-coherent (agent-scope) ops; one monolithic 32-block group barrier per
// step. Structure identical to the proven R6 kernel; only the W layout
// (tile-major blocked) differs.
// ---------------------------------------------------------------------------
__global__ __launch_bounds__(256, 2) void snn_scan(
    const float* __restrict__ inputs,
    const float* __restrict__ w_in,
    const float* __restrict__ w_out,
    const float* __restrict__ p,
    const int*   __restrict__ delays,
    const float* __restrict__ W,        // blocked (NT,KK,32) (use_W)
    const float* __restrict__ w_raw,
    const float* __restrict__ w_signs,
    const float* __restrict__ dmap,
    float*       __restrict__ ring,     // (LL6,BB,NN)
    int*         __restrict__ cnt,      // (GG*32) padded barrier counters
    float*       __restrict__ hpart,    // (2,NT,BB,NOUT)
    const float* __restrict__ inp_pre,  // (T,B,N) or null
    float*       __restrict__ out,      // (B,T,NOUT)
    int use_pre, int use_W)
{
    __shared__ __align__(16) float sa[KK * BPG];   // 48 KB; aliased as red[] post-GEMM
    __shared__ float w_out_s[32 * NOUT];           // 4 KB
    __shared__ float spk_s[BPG * 32];              // 512 B
    __shared__ float s_sign[NN];                   // 4 KB (fallback)
    __shared__ float s_in[BPG * NIN];              // 2 KB (fallback)

    const int bid  = blockIdx.x;
    const int g    = bid >> 5;          // 0..15
    const int tile = bid & 31;          // 0..31 (bid%8 == tile%8 -> XCD locality)
    const int tid  = threadIdx.x;
    const int lane = tid & 63;
    const int wv   = tid >> 6;

    const bool st = (tid < BPG * 32);   // 128 state threads
    const int  sb = tid >> 5;           // batch in group (state role)
    const int  nl = tid & 31;           // col in tile   (state role)

    const int gks = tid >> 3;           // k-split 0..31 (GEMM role)
    const int gcg = tid & 7;            // col group 0..7 (4 cols)

    float mem = 0.0f, wp = 0.0f, r = 0.0f;
    float pn = 0.0f, depr = 0.0f;
    if (st) { pn = p[tile * 32 + nl]; depr = (pn < 0.0f) ? 1.0f : 0.0f; }

    const int d0 = delays[0], d1 = delays[1], d2 = delays[2];

    for (int k = tid; k < 32 * NOUT; k += 256)
        w_out_s[k] = w_out[(tile * 32 + (k >> 5)) * NOUT + (k & 31)];
    if (!use_W)
        for (int k = tid; k < NN; k += 256) s_sign[k] = w_signs[k];
    __syncthreads();

    // blocked-W base for this thread: cols gcg*4..+3 of this tile, row kk
    const float* Wt = W + ((size_t)tile * KK) * 32 + gcg * 4;
    // fallback bases (original layouts)
    const float* Dt = dmap  + tile * 32 + gcg * 4;
    const float* Rt = w_raw + tile * 32 + gcg * 4;

    for (int t = 0; t < TT; ++t) {
        const int slot_w = t % LL6;
        const int s0 = (t - d0 + 2 * LL6) % LL6;
        const int s1 = (t - d1 + 2 * LL6) % LL6;
        const int s2 = (t - d2 + 2 * LL6) % LL6;

        // ---- phase 1: spike, publish ring (IF), wp update, ia prefetch
        bool  spk = false;
        float ia  = 0.0f;
        if (st) {
            spk = (mem - 1.0f) > 0.0f;
            const float a = spk ? (1.0f + wp) : 0.0f;
            __hip_atomic_store(ring + (((size_t)slot_w * BB + g * BPG + sb) << 10)
                                    + tile * 32 + nl,
                               a, __ATOMIC_RELAXED, __HIP_MEMORY_SCOPE_AGENT);
            wp = ALPHA_P * wp + (spk ? pn * (1.0f + depr * wp) : 0.0f);
            spk_s[tid] = spk ? 1.0f : 0.0f;
            if (use_pre)
                ia = inp_pre[((size_t)t * BB + g * BPG + sb) * NN + tile * 32 + nl];
        }
        if (!use_pre) {
            for (int k = tid; k < BPG * NIN; k += 256) {
                int b2 = k >> 7, c = k & 127;
                s_in[k] = inputs[((size_t)(g * BPG + b2) * TT + t) * NIN + c];
            }
        }
        __syncthreads();

        // ---- phase 2: readout partial for this tile
        if (st) {
            float h = 0.0f;
            #pragma unroll
            for (int n2 = 0; n2 < 32; ++n2)
                h = fmaf(spk_s[sb * 32 + n2], w_out_s[n2 * 32 + nl], h);
            __hip_atomic_store(hpart + ((((size_t)(t & 1) * NT + tile) * BB)
                                        + g * BPG + sb) * NOUT + nl,
                               h, __ATOMIC_RELAXED, __HIP_MEMORY_SCOPE_AGENT);
            if (!use_pre) {
                #pragma unroll 8
                for (int c = 0; c < NIN; ++c)
                    ia = fmaf(s_in[sb * NIN + c], w_in[c * NN + tile * 32 + nl], ia);
            }
        }
        __syncthreads();   // all waves' IF stores drained (vmcnt 0) before barrier

        // ---- group barrier: 32 blocks, one RMW each
        if (tid == 0) {
            __hip_atomic_fetch_add(&cnt[g * 32], 1, __ATOMIC_RELEASE,
                                   __HIP_MEMORY_SCOPE_AGENT);
            const int target = 32 * (t + 1);
            while (__hip_atomic_load(&cnt[g * 32], __ATOMIC_RELAXED,
                                     __HIP_MEMORY_SCOPE_AGENT) < target)
                __builtin_amdgcn_s_sleep(2);
        }
        __syncthreads();

        // ---- readout (tile-0 block of each group): integrate step t
        if (tile == 0 && st) {
            float h = 0.0f;
            for (int k3 = 0; k3 < NT; ++k3)
                h += __hip_atomic_load(hpart + ((((size_t)(t & 1) * NT + k3) * BB)
                                                + g * BPG + sb) * NOUT + nl,
                                       __ATOMIC_RELAXED, __HIP_MEMORY_SCOPE_AGENT);
            r = ALPHA_MEM_OUT * r + h;
            out[((size_t)(g * BPG + sb) * TT + t) * NOUT + nl] = r;
        }

        // ---- stage A transposed: sa[k*4 + b], 64B global segments, 2-way LDS
        {
            const int b2 = lane >> 4;       // batch 0..3
            const int eo = lane & 15;       // e offset within 16-chunk
            #pragma unroll 8
            for (int i = 0; i < 48; ++i) {
                const int c  = i * 4 + wv;          // 16-wide k-chunk 0..191
                const int kl = c * 16 + eo;         // k index 0..3071
                const int d  = kl >> 10;
                const int e  = kl & 1023;
                const int sl = (d == 0) ? s0 : ((d == 1) ? s1 : s2);
                const float v = __hip_atomic_load(
                    ring + (((size_t)sl * BB + g * BPG + b2) << 10) + e,
                    __ATOMIC_RELAXED, __HIP_MEMORY_SCOPE_AGENT);
                sa[kl * 4 + b2] = v;
            }
        }
        __syncthreads();

        // ---- GEMM: per thread 4 batches x 4 cols, k interleaved (gks + 32i)
        float4 acc0 = {0,0,0,0}, acc1 = {0,0,0,0}, acc2 = {0,0,0,0}, acc3 = {0,0,0,0};
        if (use_W) {
            #pragma unroll 4
            for (int i = 0; i < 96; ++i) {
                const int kk = gks + (i << 5);
                const float4 av = *(const float4*)&sa[kk << 2];        // 4 batches (LDS broadcast)
                const float4 wv4 = *(const float4*)(Wt + (size_t)kk * 32); // 4 cols (contiguous stream)
                acc0.x = fmaf(av.x, wv4.x, acc0.x); acc0.y = fmaf(av.x, wv4.y, acc0.y);
                acc0.z = fmaf(av.x, wv4.z, acc0.z); acc0.w = fmaf(av.x, wv4.w, acc0.w);
                acc1.x = fmaf(av.y, wv4.x, acc1.x); acc1.y = fmaf(av.y, wv4.y, acc1.y);
                acc1.z = fmaf(av.y, wv4.z, acc1.z); acc1.w = fmaf(av.y, wv4.w, acc1.w);
                acc2.x = fmaf(av.z, wv4.x, acc2.x); acc2.y = fmaf(av.z, wv4.y, acc2.y);
                acc2.z = fmaf(av.z, wv4.z, acc2.z); acc2.w = fmaf(av.z, wv4.w, acc2.w);
                acc3.x = fmaf(av.w, wv4.x, acc3.x); acc3.y = fmaf(av.w, wv4.y, acc3.y);
                acc3.z = fmaf(av.w, wv4.z, acc3.z); acc3.w = fmaf(av.w, wv4.w, acc3.w);
            }
        } else {
            #pragma unroll 2
            for (int i = 0; i < 96; ++i) {
                const int kk = gks + (i << 5);
                const int e  = kk & 1023;
                const float sg = s_sign[e];
                const float4 dm = *(const float4*)(Dt + ((size_t)kk << 10));
                const float4 wr = *(const float4*)(Rt + ((size_t)e << 10));
                float4 wv4;
                wv4.x = dm.x * (sg * fabsf(wr.x));
                wv4.y = dm.y * (sg * fabsf(wr.y));
                wv4.z = dm.z * (sg * fabsf(wr.z));
                wv4.w = dm.w * (sg * fabsf(wr.w));
                const float4 av = *(const float4*)&sa[kk << 2];
                acc0.x = fmaf(av.x, wv4.x, acc0.x); acc0.y = fmaf(av.x, wv4.y, acc0.y);
                acc0.z = fmaf(av.x, wv4.z, acc0.z); acc0.w = fmaf(av.x, wv4.w, acc0.w);
                acc1.x = fmaf(av.y, wv4.x, acc1.x); acc1.y = fmaf(av.y, wv4.y, acc1.y);
                acc1.z = fmaf(av.y, wv4.z, acc1.z); acc1.w = fmaf(av.y, wv4.w, acc1.w);
                acc2.x = fmaf(av.z, wv4.x, acc2.x); acc2.y = fmaf(av.z, wv4.y, acc2.y);
                acc2.z = fmaf(av.z, wv4.z, acc2.z); acc2.w = fmaf(av.z, wv4.w, acc2.w);
                acc3.x = fmaf(av.w, wv4.x, acc3.x); acc3.y = fmaf(av.w, wv4.y, acc3.y);
                acc3.z = fmaf(av.w, wv4.z, acc3.z); acc3.w = fmaf(av.w, wv4.w, acc3.w);
            }
        }
        __syncthreads();             // sa reads done; alias as red

        float* red = sa;             // red[o][33], o = b2*32 + gcg*4 + j  (o<128)
        {
            const int o0 = gcg * 4;
            red[(0 * 32 + o0 + 0) * 33 + gks] = acc0.x;
            red[(0 * 32 + o0 + 1) * 33 + gks] = acc0.y;
            red[(0 * 32 + o0 + 2) * 33 + gks] = acc0.z;
            red[(0 * 32 + o0 + 3) * 33 + gks] = acc0.w;
            red[(1 * 32 + o0 + 0) * 33 + gks] = acc1.x;
            red[(1 * 32 + o0 + 1) * 33 + gks] = acc1.y;
            red[(1 * 32 + o0 + 2) * 33 + gks] = acc1.z;
            red[(1 * 32 + o0 + 3) * 33 + gks] = acc1.w;
            red[(2 * 32 + o0 + 0) * 33 + gks] = acc2.x;
            red[(2 * 32 + o0 + 1) * 33 + gks] = acc2.y;
            red[(2 * 32 + o0 + 2) * 33 + gks] = acc2.z;
            red[(2 * 32 + o0 + 3) * 33 + gks] = acc2.w;
            red[(3 * 32 + o0 + 0) * 33 + gks] = acc3.x;
            red[(3 * 32 + o0 + 1) * 33 + gks] = acc3.y;
            red[(3 * 32 + o0 + 2) * 33 + gks] = acc3.z;
            red[(3 * 32 + o0 + 3) * 33 + gks] = acc3.w;
        }
        __syncthreads();

        if (st) {
            float syn = 0.0f;
            #pragma unroll
            for (int k2 = 0; k2 < 32; ++k2)
                syn += red[tid * 33 + k2];
            mem = ALPHA_MEM * mem + ia + syn - (spk ? 1.0f : 0.0f);
        }
        __syncthreads();             // red reads done before next staging
    }
}

// ---------------------------------------------------------------------------
extern "C" void kernel_launch(void* const* d_in, const int* in_sizes, int n_in,
                              void* d_out, int out_size, void* d_ws, size_t ws_size,
                              hipStream_t stream) {
    const float* inputs  = (const float*)d_in[0];
    const float* w       = (const float*)d_in[1];
    const float* w_in    = (const float*)d_in[2];
    const float* w_out   = (const float*)d_in[3];
    const float* w_signs = (const float*)d_in[4];
    const float* dmap    = (const float*)d_in[5];
    const float* p       = (const float*)d_in[6];
    const int*   delays  = (const int*)d_in[7];
    float*       outp    = (float*)d_out;

    // ws layout (floats): ring | cnt(padded) | hpart | W | inp_pre
    const size_t ring_f = (size_t)LL6 * BB * NN;          // 393216
    const size_t cnt_f  = GG * 32;                        // 512
    const size_t hp_f   = (size_t)2 * NT * BB * NOUT;     // 131072
    const size_t W_f    = (size_t)DD * NN * NN;           // 3145728
    const size_t pre_f  = (size_t)TT * BB * NN;           // 26214400

    float* ws = (float*)d_ws;
    float* ring  = ws;
    int*   cntp  = (int*)(ws + ring_f);
    float* hpart = ws + ring_f + cnt_f;
    size_t used  = ring_f + cnt_f + hp_f;

    int use_W = 0, use_pre = 0;
    float *W = nullptr, *inp_pre = nullptr;
    if (ws_size >= (used + W_f) * 4)   { use_W = 1;   W = ws + used;       used += W_f; }
    if (ws_size >= (used + pre_f) * 4) { use_pre = 1; inp_pre = ws + used; used += pre_f; }

    if (use_W) {
        const int total = DD * NN * NN;
        build_W<<<(total + 255) / 256, 256, 0, stream>>>(w, w_signs, dmap, W);
    }
    if (use_pre) {
        const int total = TT * BB * NN;
        gemm_in<<<(total + 255) / 256, 256, 0, stream>>>(inputs, w_in, inp_pre);
    }
    {
        const int total = (int)(ring_f + cnt_f);   // ring + counters
        zero_sc1<<<(total + 255) / 256, 256, 0, stream>>>(ring, total);
    }

    void* args[] = {
        (void*)&inputs, (void*)&w_in, (void*)&w_out, (void*)&p, (void*)&delays,
        (void*)&W, (void*)&w, (void*)&w_signs, (void*)&dmap,
        (void*)&ring, (void*)&cntp, (void*)&hpart, (void*)&inp_pre, (void*)&outp,
        (void*)&use_pre, (void*)&use_W
    };
    hipLaunchCooperativeKernel((const void*)snn_scan,
                               dim3(GG * NT), dim3(256), args, 0, stream);
}